// Round 12
// baseline (179.749 us; speedup 1.0000x reference)
//
#include <hip/hip_runtime.h>
#include <hip/hip_bf16.h>
#include <math.h>

typedef short bf16x8 __attribute__((ext_vector_type(8)));
typedef float f32x4 __attribute__((ext_vector_type(4)));

#define SPW 1   // stripes (16 rows) per wave in z-GEMM: 1563 blocks = 6.1/CU
#define CAP 64  // bucket capacity per row (Poisson(16): P(>64) ~ 1e-19)

static __device__ __forceinline__ float bf2f(ushort u) {
  union { unsigned i; float f; } c;
  c.i = ((unsigned)u) << 16;
  return c.f;
}

static __device__ __forceinline__ ushort f2bf(float f) {
  __hip_bfloat16 h = __float2bfloat16(f);
  return *reinterpret_cast<ushort*>(&h);
}

// ---------------------------------------------------------------------------
// z-GEMM: z[r][o] = sum_k x[r][k] * W[o][k]  (r = l*G+g); W converted inline.
// Operand-SWAPPED mfma (wf as A, af as B): lane holds z[row0+o_lo][on*16+kg*4
// +reg] -> 4 consecutive o per acc tile -> ushort4 stores (4x fewer insts).
// ---------------------------------------------------------------------------
__global__ __launch_bounds__(256) void zgemm_kernel(
    const float* __restrict__ x, const float* __restrict__ W,
    ushort* __restrict__ zb, int nstripes) {
  const int lane = threadIdx.x & 63;
  const int wid = blockIdx.x * 4 + (threadIdx.x >> 6);

  const int o_lo = lane & 15;
  const int kg = lane >> 4;

  bf16x8 wf[8][4];
#pragma unroll
  for (int on = 0; on < 8; ++on)
#pragma unroll
    for (int kc = 0; kc < 4; ++kc) {
      const float* src = W + (size_t)(on * 16 + o_lo) * 128 + kc * 32 + kg * 8;
      float4 v0 = *reinterpret_cast<const float4*>(src);
      float4 v1 = *reinterpret_cast<const float4*>(src + 4);
      bf16x8 t;
      t[0] = (short)f2bf(v0.x); t[1] = (short)f2bf(v0.y);
      t[2] = (short)f2bf(v0.z); t[3] = (short)f2bf(v0.w);
      t[4] = (short)f2bf(v1.x); t[5] = (short)f2bf(v1.y);
      t[6] = (short)f2bf(v1.z); t[7] = (short)f2bf(v1.w);
      wf[on][kc] = t;
    }

  const int s = wid * SPW;
  if (s >= nstripes) return;
  const int row0 = s << 4;

  bf16x8 af[4];
#pragma unroll
  for (int kc = 0; kc < 4; ++kc) {
    const float* src = x + (size_t)(row0 + o_lo) * 128 + kc * 32 + kg * 8;
    float4 v0 = *reinterpret_cast<const float4*>(src);
    float4 v1 = *reinterpret_cast<const float4*>(src + 4);
    bf16x8 t;
    t[0] = (short)f2bf(v0.x); t[1] = (short)f2bf(v0.y);
    t[2] = (short)f2bf(v0.z); t[3] = (short)f2bf(v0.w);
    t[4] = (short)f2bf(v1.x); t[5] = (short)f2bf(v1.y);
    t[6] = (short)f2bf(v1.z); t[7] = (short)f2bf(v1.w);
    af[kc] = t;
  }

  f32x4 acc[8];
#pragma unroll
  for (int on = 0; on < 8; ++on) acc[on] = (f32x4){0.f, 0.f, 0.f, 0.f};

#pragma unroll
  for (int kc = 0; kc < 4; ++kc)
#pragma unroll
    for (int on = 0; on < 8; ++on)
      acc[on] = __builtin_amdgcn_mfma_f32_16x16x32_bf16(wf[on][kc], af[kc],
                                                        acc[on], 0, 0, 0);

  // swapped-D layout: lane -> row r = row0 + o_lo, col o = on*16 + kg*4 + reg
  ushort* zr = zb + (size_t)(row0 + o_lo) * 128 + kg * 4;
#pragma unroll
  for (int on = 0; on < 8; ++on) {
    ushort4 st;
    st.x = f2bf(acc[on][0]);
    st.y = f2bf(acc[on][1]);
    st.z = f2bf(acc[on][2]);
    st.w = f2bf(acc[on][3]);
    *reinterpret_cast<ushort4*>(zr + on * 16) = st;
  }
}

// ---------------------------------------------------------------------------
// Bucket build: ONE pass over edges (hist + scatter fused, no scan).
// 2 edges per thread, vectorized edge loads.
// ---------------------------------------------------------------------------
__global__ __launch_bounds__(256) void bucket_kernel(
    const int* __restrict__ rows, const int* __restrict__ cols,
    const float* __restrict__ vals, int* __restrict__ counts,
    int2* __restrict__ ev, int E) {
  const int e = (blockIdx.x * 256 + threadIdx.x) * 2;
  if (e + 1 < E) {
    const int2 r2 = *reinterpret_cast<const int2*>(rows + e);
    const int2 c2 = *reinterpret_cast<const int2*>(cols + e);
    const float2 v2 = *reinterpret_cast<const float2*>(vals + e);
    int p0 = atomicAdd(&counts[r2.x], 1);
    int p1 = atomicAdd(&counts[r2.y], 1);
    if (p0 < CAP)
      ev[(size_t)r2.x * CAP + p0] = make_int2(c2.x << 8, __float_as_int(v2.x));
    if (p1 < CAP)
      ev[(size_t)r2.y * CAP + p1] = make_int2(c2.y << 8, __float_as_int(v2.y));
  } else if (e < E) {
    int r = rows[e];
    int pos = atomicAdd(&counts[r], 1);
    if (pos < CAP)
      ev[(size_t)r * CAP + pos] =
          make_int2(cols[e] << 8, __float_as_int(vals[e]));
  }
}

// ---------------------------------------------------------------------------
// Fused gather + bias + SiLU + LayerNorm.  One wave per row g.
// Lane -> (l = lane>>5, q = lane&31): 4 elems of h[l][g][:].
// ---------------------------------------------------------------------------
__global__ __launch_bounds__(256) void gather_fused_kernel(
    const ushort* __restrict__ zb, const int* __restrict__ counts,
    const int2* __restrict__ ev, const float* __restrict__ b,
    const float* __restrict__ gamma, const float* __restrict__ beta,
    float* __restrict__ out, int G, int GD) {
  int g = blockIdx.x * 4 + (threadIdx.x >> 6);
  if (g >= G) return;
  const int lane = threadIdx.x & 63;
  const int l = lane >> 5;
  const int q = lane & 31;
  const char* zbase = (const char*)(zb + (size_t)l * GD);
  const uint qoff = (uint)q << 3;

  const int2* evr = ev + (size_t)g * CAP;
  int n = counts[g];
  if (n > CAP) n = CAP;
  float4 acc = make_float4(0.f, 0.f, 0.f, 0.f);

  int i = 0;
  for (; i + 3 < n; i += 4) {
    int2 e0 = evr[i], e1 = evr[i + 1], e2 = evr[i + 2], e3 = evr[i + 3];
    ushort4 a0 = *reinterpret_cast<const ushort4*>(zbase + ((uint)e0.x + qoff));
    ushort4 a1 = *reinterpret_cast<const ushort4*>(zbase + ((uint)e1.x + qoff));
    ushort4 a2 = *reinterpret_cast<const ushort4*>(zbase + ((uint)e2.x + qoff));
    ushort4 a3 = *reinterpret_cast<const ushort4*>(zbase + ((uint)e3.x + qoff));
    float v0 = __int_as_float(e0.y), v1 = __int_as_float(e1.y);
    float v2 = __int_as_float(e2.y), v3 = __int_as_float(e3.y);
    acc.x += v0 * bf2f(a0.x) + v1 * bf2f(a1.x) + v2 * bf2f(a2.x) + v3 * bf2f(a3.x);
    acc.y += v0 * bf2f(a0.y) + v1 * bf2f(a1.y) + v2 * bf2f(a2.y) + v3 * bf2f(a3.y);
    acc.z += v0 * bf2f(a0.z) + v1 * bf2f(a1.z) + v2 * bf2f(a2.z) + v3 * bf2f(a3.z);
    acc.w += v0 * bf2f(a0.w) + v1 * bf2f(a1.w) + v2 * bf2f(a2.w) + v3 * bf2f(a3.w);
  }
  for (; i < n; ++i) {
    int2 e0 = evr[i];
    float v0 = __int_as_float(e0.y);
    ushort4 a0 = *reinterpret_cast<const ushort4*>(zbase + ((uint)e0.x + qoff));
    acc.x += v0 * bf2f(a0.x);
    acc.y += v0 * bf2f(a0.y);
    acc.z += v0 * bf2f(a0.z);
    acc.w += v0 * bf2f(a0.w);
  }

  // epilogue: bias + SiLU + LayerNorm (within the 32-lane half-wave)
  const int d0 = q * 4;
  const float4 bb = *reinterpret_cast<const float4*>(b + d0);
  float4 s;
  {
    float h0 = acc.x + bb.x, h1 = acc.y + bb.y;
    float h2 = acc.z + bb.z, h3 = acc.w + bb.w;
    s.x = h0 / (1.f + expf(-h0));
    s.y = h1 / (1.f + expf(-h1));
    s.z = h2 / (1.f + expf(-h2));
    s.w = h3 / (1.f + expf(-h3));
  }
  float sum = s.x + s.y + s.z + s.w;
  float sq = s.x * s.x + s.y * s.y + s.z * s.z + s.w * s.w;
#pragma unroll
  for (int m = 1; m <= 16; m <<= 1) {
    sum += __shfl_xor(sum, m);
    sq += __shfl_xor(sq, m);
  }
  const float mu = sum * (1.f / 128.f);
  const float var = sq * (1.f / 128.f) - mu * mu;
  const float inv = rsqrtf(var + 1e-5f);
  const float4 gm = *reinterpret_cast<const float4*>(gamma + d0);
  const float4 bt = *reinterpret_cast<const float4*>(beta + d0);
  float4 o;
  o.x = (s.x - mu) * inv * gm.x + bt.x;
  o.y = (s.y - mu) * inv * gm.y + bt.y;
  o.z = (s.z - mu) * inv * gm.z + bt.z;
  o.w = (s.w - mu) * inv * gm.w + bt.w;
  *reinterpret_cast<float4*>(out + (size_t)l * GD + (size_t)g * 128 + d0) = o;
}

// ---------------------------------------------------------------------------
extern "C" void kernel_launch(void* const* d_in, const int* in_sizes, int n_in,
                              void* d_out, int out_size, void* d_ws,
                              size_t ws_size, hipStream_t stream) {
  const float* x = (const float*)d_in[0];
  const int* rows = (const int*)d_in[1];
  const int* cols = (const int*)d_in[2];
  const float* vals = (const float*)d_in[3];
  const float* W = (const float*)d_in[4];
  const float* b = (const float*)d_in[5];
  const float* gamma = (const float*)d_in[6];
  const float* beta = (const float*)d_in[7];

  const int E = in_sizes[1];
  const int G = in_sizes[0] / 256;  // L=2, D=128
  const int GD = G * 128;

  // workspace layout:  zb (25.6 MB) | counts (200 KB) | ev (25.6 MB)
  char* ws = (char*)d_ws;
  ushort* zb = (ushort*)ws;                    // 2G*128 bf16
  int* counts = (int*)(zb + (size_t)2 * GD);   // G
  int* counts_end = counts + G + (G & 1);      // 8B align
  int2* ev = (int2*)counts_end;                // G*CAP int2

  (void)hipMemsetAsync(counts, 0, (size_t)G * sizeof(int), stream);
  bucket_kernel<<<(E / 2 + 255) / 256 + 1, 256, 0, stream>>>(
      rows, cols, vals, counts, ev, E);
  const int nstripes = (G * 2) / 16;
  zgemm_kernel<<<(nstripes + 4 * SPW - 1) / (4 * SPW), 256, 0, stream>>>(
      x, W, zb, nstripes);
  gather_fused_kernel<<<(G + 3) / 4, 256, 0, stream>>>(zb, counts, ev, b,
                                                       gamma, beta,
                                                       (float*)d_out, G, GD);
}

// Round 13
// 156.816 us; speedup vs baseline: 1.1462x; 1.1462x over previous
//
#include <hip/hip_runtime.h>
#include <hip/hip_bf16.h>
#include <math.h>

typedef short bf16x8 __attribute__((ext_vector_type(8)));
typedef float f32x4 __attribute__((ext_vector_type(4)));

#define SPW 2   // stripes (16 rows) per wave in z-GEMM: 782 blocks = 3.05/CU
#define CAP 64  // bucket capacity per row (Poisson(16): P(>64) ~ 1e-19)

static __device__ __forceinline__ float bf2f(ushort u) {
  union { unsigned i; float f; } c;
  c.i = ((unsigned)u) << 16;
  return c.f;
}

static __device__ __forceinline__ ushort f2bf(float f) {
  __hip_bfloat16 h = __float2bfloat16(f);
  return *reinterpret_cast<ushort*>(&h);
}

// ---------------------------------------------------------------------------
// Prep: W fp32->bf16 (16K elems) + zero counts.  Replaces the memset.
// ---------------------------------------------------------------------------
__global__ __launch_bounds__(256) void prep_kernel(const float* __restrict__ W,
                                                   ushort* __restrict__ Wb,
                                                   int* __restrict__ counts,
                                                   int G) {
  int t = blockIdx.x * 256 + threadIdx.x;
  if (t < 16384) Wb[t] = f2bf(W[t]);
  for (int i = t; i < G; i += (int)gridDim.x * 256) counts[i] = 0;
}

// ---------------------------------------------------------------------------
// Bucket build: ONE pass over edges (hist + scatter fused, no scan).
// 2 edges per thread, vectorized edge loads.
// ---------------------------------------------------------------------------
__global__ __launch_bounds__(256) void bucket_kernel(
    const int* __restrict__ rows, const int* __restrict__ cols,
    const float* __restrict__ vals, int* __restrict__ counts,
    int2* __restrict__ ev, int E) {
  const int e = (blockIdx.x * 256 + threadIdx.x) * 2;
  if (e + 1 < E) {
    const int2 r2 = *reinterpret_cast<const int2*>(rows + e);
    const int2 c2 = *reinterpret_cast<const int2*>(cols + e);
    const float2 v2 = *reinterpret_cast<const float2*>(vals + e);
    int p0 = atomicAdd(&counts[r2.x], 1);
    int p1 = atomicAdd(&counts[r2.y], 1);
    if (p0 < CAP)
      ev[(size_t)r2.x * CAP + p0] = make_int2(c2.x << 8, __float_as_int(v2.x));
    if (p1 < CAP)
      ev[(size_t)r2.y * CAP + p1] = make_int2(c2.y << 8, __float_as_int(v2.y));
  } else if (e < E) {
    int r = rows[e];
    int pos = atomicAdd(&counts[r], 1);
    if (pos < CAP)
      ev[(size_t)r * CAP + pos] =
          make_int2(cols[e] << 8, __float_as_int(vals[e]));
  }
}

// ---------------------------------------------------------------------------
// z-GEMM: z[r][o] = sum_k x[r][k] * W[o][k]  (r = l*G+g).
// W pre-converted bf16 -> fragment loads are pure 16B L1/L2 hits, no cvt.
// Operand-SWAPPED mfma (wf as A, af as B): lane holds 4 consecutive o per
// acc tile -> ushort4 stores.
// ---------------------------------------------------------------------------
__global__ __launch_bounds__(256) void zgemm_kernel(
    const float* __restrict__ x, const ushort* __restrict__ Wb,
    ushort* __restrict__ zb, int nstripes) {
  const int lane = threadIdx.x & 63;
  const int wid = blockIdx.x * 4 + (threadIdx.x >> 6);

  const int o_lo = lane & 15;
  const int kg = lane >> 4;

  bf16x8 wf[8][4];
#pragma unroll
  for (int on = 0; on < 8; ++on)
#pragma unroll
    for (int kc = 0; kc < 4; ++kc)
      wf[on][kc] = *reinterpret_cast<const bf16x8*>(
          Wb + (size_t)(on * 16 + o_lo) * 128 + kc * 32 + kg * 8);

  for (int i = 0; i < SPW; ++i) {
    const int s = wid * SPW + i;
    if (s >= nstripes) return;
    const int row0 = s << 4;

    bf16x8 af[4];
#pragma unroll
    for (int kc = 0; kc < 4; ++kc) {
      const float* src = x + (size_t)(row0 + o_lo) * 128 + kc * 32 + kg * 8;
      float4 v0 = *reinterpret_cast<const float4*>(src);
      float4 v1 = *reinterpret_cast<const float4*>(src + 4);
      bf16x8 t;
      t[0] = (short)f2bf(v0.x); t[1] = (short)f2bf(v0.y);
      t[2] = (short)f2bf(v0.z); t[3] = (short)f2bf(v0.w);
      t[4] = (short)f2bf(v1.x); t[5] = (short)f2bf(v1.y);
      t[6] = (short)f2bf(v1.z); t[7] = (short)f2bf(v1.w);
      af[kc] = t;
    }

    f32x4 acc[8];
#pragma unroll
    for (int on = 0; on < 8; ++on) acc[on] = (f32x4){0.f, 0.f, 0.f, 0.f};

#pragma unroll
    for (int kc = 0; kc < 4; ++kc)
#pragma unroll
      for (int on = 0; on < 8; ++on)
        acc[on] = __builtin_amdgcn_mfma_f32_16x16x32_bf16(wf[on][kc], af[kc],
                                                          acc[on], 0, 0, 0);

    // swapped-D layout: lane -> row row0 + o_lo, col o = on*16 + kg*4 + reg
    ushort* zr = zb + (size_t)(row0 + o_lo) * 128 + kg * 4;
#pragma unroll
    for (int on = 0; on < 8; ++on) {
      ushort4 st;
      st.x = f2bf(acc[on][0]);
      st.y = f2bf(acc[on][1]);
      st.z = f2bf(acc[on][2]);
      st.w = f2bf(acc[on][3]);
      *reinterpret_cast<ushort4*>(zr + on * 16) = st;
    }
  }
}

// ---------------------------------------------------------------------------
// Fused gather + bias + SiLU + LayerNorm.  One wave per row g.
// Lane -> (l = lane>>5, q = lane&31): 4 elems of h[l][g][:].
// ---------------------------------------------------------------------------
__global__ __launch_bounds__(256) void gather_fused_kernel(
    const ushort* __restrict__ zb, const int* __restrict__ counts,
    const int2* __restrict__ ev, const float* __restrict__ b,
    const float* __restrict__ gamma, const float* __restrict__ beta,
    float* __restrict__ out, int G, int GD) {
  int g = blockIdx.x * 4 + (threadIdx.x >> 6);
  if (g >= G) return;
  const int lane = threadIdx.x & 63;
  const int l = lane >> 5;
  const int q = lane & 31;
  const char* zbase = (const char*)(zb + (size_t)l * GD);
  const uint qoff = (uint)q << 3;

  const int2* evr = ev + (size_t)g * CAP;
  int n = counts[g];
  if (n > CAP) n = CAP;
  float4 acc = make_float4(0.f, 0.f, 0.f, 0.f);

  int i = 0;
  for (; i + 3 < n; i += 4) {
    int2 e0 = evr[i], e1 = evr[i + 1], e2 = evr[i + 2], e3 = evr[i + 3];
    ushort4 a0 = *reinterpret_cast<const ushort4*>(zbase + ((uint)e0.x + qoff));
    ushort4 a1 = *reinterpret_cast<const ushort4*>(zbase + ((uint)e1.x + qoff));
    ushort4 a2 = *reinterpret_cast<const ushort4*>(zbase + ((uint)e2.x + qoff));
    ushort4 a3 = *reinterpret_cast<const ushort4*>(zbase + ((uint)e3.x + qoff));
    float v0 = __int_as_float(e0.y), v1 = __int_as_float(e1.y);
    float v2 = __int_as_float(e2.y), v3 = __int_as_float(e3.y);
    acc.x += v0 * bf2f(a0.x) + v1 * bf2f(a1.x) + v2 * bf2f(a2.x) + v3 * bf2f(a3.x);
    acc.y += v0 * bf2f(a0.y) + v1 * bf2f(a1.y) + v2 * bf2f(a2.y) + v3 * bf2f(a3.y);
    acc.z += v0 * bf2f(a0.z) + v1 * bf2f(a1.z) + v2 * bf2f(a2.z) + v3 * bf2f(a3.z);
    acc.w += v0 * bf2f(a0.w) + v1 * bf2f(a1.w) + v2 * bf2f(a2.w) + v3 * bf2f(a3.w);
  }
  for (; i < n; ++i) {
    int2 e0 = evr[i];
    float v0 = __int_as_float(e0.y);
    ushort4 a0 = *reinterpret_cast<const ushort4*>(zbase + ((uint)e0.x + qoff));
    acc.x += v0 * bf2f(a0.x);
    acc.y += v0 * bf2f(a0.y);
    acc.z += v0 * bf2f(a0.z);
    acc.w += v0 * bf2f(a0.w);
  }

  // epilogue: bias + SiLU + LayerNorm (within the 32-lane half-wave)
  const int d0 = q * 4;
  const float4 bb = *reinterpret_cast<const float4*>(b + d0);
  float4 s;
  {
    float h0 = acc.x + bb.x, h1 = acc.y + bb.y;
    float h2 = acc.z + bb.z, h3 = acc.w + bb.w;
    s.x = h0 / (1.f + expf(-h0));
    s.y = h1 / (1.f + expf(-h1));
    s.z = h2 / (1.f + expf(-h2));
    s.w = h3 / (1.f + expf(-h3));
  }
  float sum = s.x + s.y + s.z + s.w;
  float sq = s.x * s.x + s.y * s.y + s.z * s.z + s.w * s.w;
#pragma unroll
  for (int m = 1; m <= 16; m <<= 1) {
    sum += __shfl_xor(sum, m);
    sq += __shfl_xor(sq, m);
  }
  const float mu = sum * (1.f / 128.f);
  const float var = sq * (1.f / 128.f) - mu * mu;
  const float inv = rsqrtf(var + 1e-5f);
  const float4 gm = *reinterpret_cast<const float4*>(gamma + d0);
  const float4 bt = *reinterpret_cast<const float4*>(beta + d0);
  float4 o;
  o.x = (s.x - mu) * inv * gm.x + bt.x;
  o.y = (s.y - mu) * inv * gm.y + bt.y;
  o.z = (s.z - mu) * inv * gm.z + bt.z;
  o.w = (s.w - mu) * inv * gm.w + bt.w;
  *reinterpret_cast<float4*>(out + (size_t)l * GD + (size_t)g * 128 + d0) = o;
}

// ---------------------------------------------------------------------------
extern "C" void kernel_launch(void* const* d_in, const int* in_sizes, int n_in,
                              void* d_out, int out_size, void* d_ws,
                              size_t ws_size, hipStream_t stream) {
  const float* x = (const float*)d_in[0];
  const int* rows = (const int*)d_in[1];
  const int* cols = (const int*)d_in[2];
  const float* vals = (const float*)d_in[3];
  const float* W = (const float*)d_in[4];
  const float* b = (const float*)d_in[5];
  const float* gamma = (const float*)d_in[6];
  const float* beta = (const float*)d_in[7];

  const int E = in_sizes[1];
  const int G = in_sizes[0] / 256;  // L=2, D=128
  const int GD = G * 128;

  // workspace layout:  zb (25.6 MB) | counts | Wb | ev (25.6 MB)
  char* ws = (char*)d_ws;
  ushort* zb = (ushort*)ws;                      // 2G*128 bf16
  int* counts = (int*)(zb + (size_t)2 * GD);     // G
  ushort* Wb = (ushort*)(counts + G + (G & 1));  // 16384 bf16 (32 KB)
  int2* ev = (int2*)(Wb + 16384);                // G*CAP int2

  prep_kernel<<<256, 256, 0, stream>>>(W, Wb, counts, G);
  bucket_kernel<<<(E / 2 + 255) / 256 + 1, 256, 0, stream>>>(
      rows, cols, vals, counts, ev, E);
  const int nstripes = (G * 2) / 16;
  zgemm_kernel<<<(nstripes + 4 * SPW - 1) / (4 * SPW), 256, 0, stream>>>(
      x, Wb, zb, nstripes);
  gather_fused_kernel<<<(G + 3) / 4, 256, 0, stream>>>(zb, counts, ev, b,
                                                       gamma, beta,
                                                       (float*)d_out, G, GD);
}

// Round 14
// 151.666 us; speedup vs baseline: 1.1852x; 1.0340x over previous
//
#include <hip/hip_runtime.h>
#include <hip/hip_bf16.h>
#include <math.h>

typedef short bf16x8 __attribute__((ext_vector_type(8)));
typedef float f32x4 __attribute__((ext_vector_type(4)));

#define SPW 2   // stripes (16 rows) per wave in z-GEMM: 782 blocks = 3.05/CU
#define CAP 64  // bucket capacity per row (Poisson(16): P(>64) ~ 1e-19)

static __device__ __forceinline__ float bf2f(ushort u) {
  union { unsigned i; float f; } c;
  c.i = ((unsigned)u) << 16;
  return c.f;
}

static __device__ __forceinline__ ushort f2bf(float f) {
  __hip_bfloat16 h = __float2bfloat16(f);
  return *reinterpret_cast<ushort*>(&h);
}

// ---------------------------------------------------------------------------
// Prep: W fp32->bf16 (16K elems) + zero counts.  Replaces the memset.
// ---------------------------------------------------------------------------
__global__ __launch_bounds__(256) void prep_kernel(const float* __restrict__ W,
                                                   ushort* __restrict__ Wb,
                                                   int* __restrict__ counts,
                                                   int G) {
  int t = blockIdx.x * 256 + threadIdx.x;
  if (t < 16384) Wb[t] = f2bf(W[t]);
  for (int i = t; i < G; i += (int)gridDim.x * 256) counts[i] = 0;
}

// ---------------------------------------------------------------------------
// Bucket build: ONE pass over edges (hist + scatter fused, no scan).
// 1 edge per thread: max independent atomic chains in flight (2/thread
// regressed 40->66us -- atomic-bound kernels want TLP, not ILP).
// ---------------------------------------------------------------------------
__global__ __launch_bounds__(256) void bucket_kernel(
    const int* __restrict__ rows, const int* __restrict__ cols,
    const float* __restrict__ vals, int* __restrict__ counts,
    int2* __restrict__ ev, int E) {
  int e = blockIdx.x * 256 + threadIdx.x;
  if (e >= E) return;
  int r = rows[e];
  int pos = atomicAdd(&counts[r], 1);
  if (pos < CAP)
    ev[(size_t)r * CAP + pos] = make_int2(cols[e] << 8, __float_as_int(vals[e]));
}

// ---------------------------------------------------------------------------
// z-GEMM: z[r][o] = sum_k x[r][k] * W[o][k]  (r = l*G+g).
// W pre-converted bf16 -> fragment loads are pure 16B L1/L2 hits, no cvt.
// Operand-SWAPPED mfma (wf as A, af as B): lane holds 4 consecutive o per
// acc tile -> ushort4 stores.
// ---------------------------------------------------------------------------
__global__ __launch_bounds__(256) void zgemm_kernel(
    const float* __restrict__ x, const ushort* __restrict__ Wb,
    ushort* __restrict__ zb, int nstripes) {
  const int lane = threadIdx.x & 63;
  const int wid = blockIdx.x * 4 + (threadIdx.x >> 6);

  const int o_lo = lane & 15;
  const int kg = lane >> 4;

  bf16x8 wf[8][4];
#pragma unroll
  for (int on = 0; on < 8; ++on)
#pragma unroll
    for (int kc = 0; kc < 4; ++kc)
      wf[on][kc] = *reinterpret_cast<const bf16x8*>(
          Wb + (size_t)(on * 16 + o_lo) * 128 + kc * 32 + kg * 8);

  for (int i = 0; i < SPW; ++i) {
    const int s = wid * SPW + i;
    if (s >= nstripes) return;
    const int row0 = s << 4;

    bf16x8 af[4];
#pragma unroll
    for (int kc = 0; kc < 4; ++kc) {
      const float* src = x + (size_t)(row0 + o_lo) * 128 + kc * 32 + kg * 8;
      float4 v0 = *reinterpret_cast<const float4*>(src);
      float4 v1 = *reinterpret_cast<const float4*>(src + 4);
      bf16x8 t;
      t[0] = (short)f2bf(v0.x); t[1] = (short)f2bf(v0.y);
      t[2] = (short)f2bf(v0.z); t[3] = (short)f2bf(v0.w);
      t[4] = (short)f2bf(v1.x); t[5] = (short)f2bf(v1.y);
      t[6] = (short)f2bf(v1.z); t[7] = (short)f2bf(v1.w);
      af[kc] = t;
    }

    f32x4 acc[8];
#pragma unroll
    for (int on = 0; on < 8; ++on) acc[on] = (f32x4){0.f, 0.f, 0.f, 0.f};

#pragma unroll
    for (int kc = 0; kc < 4; ++kc)
#pragma unroll
      for (int on = 0; on < 8; ++on)
        acc[on] = __builtin_amdgcn_mfma_f32_16x16x32_bf16(wf[on][kc], af[kc],
                                                          acc[on], 0, 0, 0);

    // swapped-D layout: lane -> row row0 + o_lo, col o = on*16 + kg*4 + reg
    ushort* zr = zb + (size_t)(row0 + o_lo) * 128 + kg * 4;
#pragma unroll
    for (int on = 0; on < 8; ++on) {
      ushort4 st;
      st.x = f2bf(acc[on][0]);
      st.y = f2bf(acc[on][1]);
      st.z = f2bf(acc[on][2]);
      st.w = f2bf(acc[on][3]);
      *reinterpret_cast<ushort4*>(zr + on * 16) = st;
    }
  }
}

// ---------------------------------------------------------------------------
// Fused gather + bias + SiLU + LayerNorm.  One wave per row g.
// Lane -> (l = lane>>5, q = lane&31): 4 elems of h[l][g][:].
// ---------------------------------------------------------------------------
__global__ __launch_bounds__(256) void gather_fused_kernel(
    const ushort* __restrict__ zb, const int* __restrict__ counts,
    const int2* __restrict__ ev, const float* __restrict__ b,
    const float* __restrict__ gamma, const float* __restrict__ beta,
    float* __restrict__ out, int G, int GD) {
  int g = blockIdx.x * 4 + (threadIdx.x >> 6);
  if (g >= G) return;
  const int lane = threadIdx.x & 63;
  const int l = lane >> 5;
  const int q = lane & 31;
  const char* zbase = (const char*)(zb + (size_t)l * GD);
  const uint qoff = (uint)q << 3;

  const int2* evr = ev + (size_t)g * CAP;
  int n = counts[g];
  if (n > CAP) n = CAP;
  float4 acc = make_float4(0.f, 0.f, 0.f, 0.f);

  int i = 0;
  for (; i + 3 < n; i += 4) {
    int2 e0 = evr[i], e1 = evr[i + 1], e2 = evr[i + 2], e3 = evr[i + 3];
    ushort4 a0 = *reinterpret_cast<const ushort4*>(zbase + ((uint)e0.x + qoff));
    ushort4 a1 = *reinterpret_cast<const ushort4*>(zbase + ((uint)e1.x + qoff));
    ushort4 a2 = *reinterpret_cast<const ushort4*>(zbase + ((uint)e2.x + qoff));
    ushort4 a3 = *reinterpret_cast<const ushort4*>(zbase + ((uint)e3.x + qoff));
    float v0 = __int_as_float(e0.y), v1 = __int_as_float(e1.y);
    float v2 = __int_as_float(e2.y), v3 = __int_as_float(e3.y);
    acc.x += v0 * bf2f(a0.x) + v1 * bf2f(a1.x) + v2 * bf2f(a2.x) + v3 * bf2f(a3.x);
    acc.y += v0 * bf2f(a0.y) + v1 * bf2f(a1.y) + v2 * bf2f(a2.y) + v3 * bf2f(a3.y);
    acc.z += v0 * bf2f(a0.z) + v1 * bf2f(a1.z) + v2 * bf2f(a2.z) + v3 * bf2f(a3.z);
    acc.w += v0 * bf2f(a0.w) + v1 * bf2f(a1.w) + v2 * bf2f(a2.w) + v3 * bf2f(a3.w);
  }
  for (; i < n; ++i) {
    int2 e0 = evr[i];
    float v0 = __int_as_float(e0.y);
    ushort4 a0 = *reinterpret_cast<const ushort4*>(zbase + ((uint)e0.x + qoff));
    acc.x += v0 * bf2f(a0.x);
    acc.y += v0 * bf2f(a0.y);
    acc.z += v0 * bf2f(a0.z);
    acc.w += v0 * bf2f(a0.w);
  }

  // epilogue: bias + SiLU + LayerNorm (within the 32-lane half-wave)
  const int d0 = q * 4;
  const float4 bb = *reinterpret_cast<const float4*>(b + d0);
  float4 s;
  {
    float h0 = acc.x + bb.x, h1 = acc.y + bb.y;
    float h2 = acc.z + bb.z, h3 = acc.w + bb.w;
    s.x = h0 / (1.f + expf(-h0));
    s.y = h1 / (1.f + expf(-h1));
    s.z = h2 / (1.f + expf(-h2));
    s.w = h3 / (1.f + expf(-h3));
  }
  float sum = s.x + s.y + s.z + s.w;
  float sq = s.x * s.x + s.y * s.y + s.z * s.z + s.w * s.w;
#pragma unroll
  for (int m = 1; m <= 16; m <<= 1) {
    sum += __shfl_xor(sum, m);
    sq += __shfl_xor(sq, m);
  }
  const float mu = sum * (1.f / 128.f);
  const float var = sq * (1.f / 128.f) - mu * mu;
  const float inv = rsqrtf(var + 1e-5f);
  const float4 gm = *reinterpret_cast<const float4*>(gamma + d0);
  const float4 bt = *reinterpret_cast<const float4*>(beta + d0);
  float4 o;
  o.x = (s.x - mu) * inv * gm.x + bt.x;
  o.y = (s.y - mu) * inv * gm.y + bt.y;
  o.z = (s.z - mu) * inv * gm.z + bt.z;
  o.w = (s.w - mu) * inv * gm.w + bt.w;
  *reinterpret_cast<float4*>(out + (size_t)l * GD + (size_t)g * 128 + d0) = o;
}

// ---------------------------------------------------------------------------
extern "C" void kernel_launch(void* const* d_in, const int* in_sizes, int n_in,
                              void* d_out, int out_size, void* d_ws,
                              size_t ws_size, hipStream_t stream) {
  const float* x = (const float*)d_in[0];
  const int* rows = (const int*)d_in[1];
  const int* cols = (const int*)d_in[2];
  const float* vals = (const float*)d_in[3];
  const float* W = (const float*)d_in[4];
  const float* b = (const float*)d_in[5];
  const float* gamma = (const float*)d_in[6];
  const float* beta = (const float*)d_in[7];

  const int E = in_sizes[1];
  const int G = in_sizes[0] / 256;  // L=2, D=128
  const int GD = G * 128;

  // workspace layout:  zb (25.6 MB) | counts | Wb | ev (25.6 MB)
  char* ws = (char*)d_ws;
  ushort* zb = (ushort*)ws;                      // 2G*128 bf16
  int* counts = (int*)(zb + (size_t)2 * GD);     // G
  ushort* Wb = (ushort*)(counts + G + (G & 1));  // 16384 bf16 (32 KB)
  int2* ev = (int2*)(Wb + 16384);                // G*CAP int2

  prep_kernel<<<256, 256, 0, stream>>>(W, Wb, counts, G);
  bucket_kernel<<<(E + 255) / 256, 256, 0, stream>>>(rows, cols, vals, counts,
                                                     ev, E);
  const int nstripes = (G * 2) / 16;
  zgemm_kernel<<<(nstripes + 4 * SPW - 1) / (4 * SPW), 256, 0, stream>>>(
      x, Wb, zb, nstripes);
  gather_fused_kernel<<<(G + 3) / 4, 256, 0, stream>>>(zb, counts, ev, b,
                                                       gamma, beta,
                                                       (float*)d_out, G, GD);
}

// Round 15
// 146.594 us; speedup vs baseline: 1.2262x; 1.0346x over previous
//
#include <hip/hip_runtime.h>
#include <hip/hip_bf16.h>
#include <math.h>

typedef short bf16x8 __attribute__((ext_vector_type(8)));
typedef float f32x4 __attribute__((ext_vector_type(4)));

#define SPW 2     // stripes (16 rows) per wave in z-GEMM: 782 blocks = 3.05/CU
#define CAP 64    // bucket capacity per row (Poisson(16): P(>64) ~ 1e-19)
#define CSTR 16   // counter stride in ints (64 B): 1 counter per cache line

static __device__ __forceinline__ float bf2f(ushort u) {
  union { unsigned i; float f; } c;
  c.i = ((unsigned)u) << 16;
  return c.f;
}

static __device__ __forceinline__ ushort f2bf(float f) {
  __hip_bfloat16 h = __float2bfloat16(f);
  return *reinterpret_cast<ushort*>(&h);
}

// ---------------------------------------------------------------------------
// Prep: W fp32->bf16 (16K elems) + zero padded counts (G*CSTR ints, 3.2 MB).
// ---------------------------------------------------------------------------
__global__ __launch_bounds__(256) void prep_kernel(const float* __restrict__ W,
                                                   ushort* __restrict__ Wb,
                                                   int* __restrict__ counts,
                                                   int n_counts) {
  int t = blockIdx.x * 256 + threadIdx.x;
  if (t < 16384) Wb[t] = f2bf(W[t]);
  for (int i = t; i < n_counts; i += (int)gridDim.x * 256) counts[i] = 0;
}

// ---------------------------------------------------------------------------
// Bucket build: ONE pass over edges.  Counters padded to 64 B apart ->
// engages ~16x more fabric atomic slices, no same-line serialization.
// ---------------------------------------------------------------------------
__global__ __launch_bounds__(256) void bucket_kernel(
    const int* __restrict__ rows, const int* __restrict__ cols,
    const float* __restrict__ vals, int* __restrict__ counts,
    int2* __restrict__ ev, int E) {
  int e = blockIdx.x * 256 + threadIdx.x;
  if (e >= E) return;
  int r = rows[e];
  int pos = atomicAdd(&counts[r * CSTR], 1);
  if (pos < CAP)
    ev[(size_t)r * CAP + pos] = make_int2(cols[e] << 8, __float_as_int(vals[e]));
}

// ---------------------------------------------------------------------------
// z-GEMM: z[r][o] = sum_k x[r][k] * W[o][k]  (r = l*G+g).
// W pre-converted bf16 (register-resident frags); operand-swapped mfma ->
// lane holds 4 consecutive o per acc tile -> ushort4 stores.
// ---------------------------------------------------------------------------
__global__ __launch_bounds__(256) void zgemm_kernel(
    const float* __restrict__ x, const ushort* __restrict__ Wb,
    ushort* __restrict__ zb, int nstripes) {
  const int lane = threadIdx.x & 63;
  const int wid = blockIdx.x * 4 + (threadIdx.x >> 6);

  const int o_lo = lane & 15;
  const int kg = lane >> 4;

  bf16x8 wf[8][4];
#pragma unroll
  for (int on = 0; on < 8; ++on)
#pragma unroll
    for (int kc = 0; kc < 4; ++kc)
      wf[on][kc] = *reinterpret_cast<const bf16x8*>(
          Wb + (size_t)(on * 16 + o_lo) * 128 + kc * 32 + kg * 8);

  for (int i = 0; i < SPW; ++i) {
    const int s = wid * SPW + i;
    if (s >= nstripes) return;
    const int row0 = s << 4;

    bf16x8 af[4];
#pragma unroll
    for (int kc = 0; kc < 4; ++kc) {
      const float* src = x + (size_t)(row0 + o_lo) * 128 + kc * 32 + kg * 8;
      float4 v0 = *reinterpret_cast<const float4*>(src);
      float4 v1 = *reinterpret_cast<const float4*>(src + 4);
      bf16x8 t;
      t[0] = (short)f2bf(v0.x); t[1] = (short)f2bf(v0.y);
      t[2] = (short)f2bf(v0.z); t[3] = (short)f2bf(v0.w);
      t[4] = (short)f2bf(v1.x); t[5] = (short)f2bf(v1.y);
      t[6] = (short)f2bf(v1.z); t[7] = (short)f2bf(v1.w);
      af[kc] = t;
    }

    f32x4 acc[8];
#pragma unroll
    for (int on = 0; on < 8; ++on) acc[on] = (f32x4){0.f, 0.f, 0.f, 0.f};

#pragma unroll
    for (int kc = 0; kc < 4; ++kc)
#pragma unroll
      for (int on = 0; on < 8; ++on)
        acc[on] = __builtin_amdgcn_mfma_f32_16x16x32_bf16(wf[on][kc], af[kc],
                                                          acc[on], 0, 0, 0);

    // swapped-D layout: lane -> row row0 + o_lo, col o = on*16 + kg*4 + reg
    ushort* zr = zb + (size_t)(row0 + o_lo) * 128 + kg * 4;
#pragma unroll
    for (int on = 0; on < 8; ++on) {
      ushort4 st;
      st.x = f2bf(acc[on][0]);
      st.y = f2bf(acc[on][1]);
      st.z = f2bf(acc[on][2]);
      st.w = f2bf(acc[on][3]);
      *reinterpret_cast<ushort4*>(zr + on * 16) = st;
    }
  }
}

// ---------------------------------------------------------------------------
// Fused gather + bias + SiLU + LayerNorm.  One wave per row g.
// Lane -> (l = lane>>5, q = lane&31): 4 elems of h[l][g][:].
// ---------------------------------------------------------------------------
__global__ __launch_bounds__(256) void gather_fused_kernel(
    const ushort* __restrict__ zb, const int* __restrict__ counts,
    const int2* __restrict__ ev, const float* __restrict__ b,
    const float* __restrict__ gamma, const float* __restrict__ beta,
    float* __restrict__ out, int G, int GD) {
  int g = blockIdx.x * 4 + (threadIdx.x >> 6);
  if (g >= G) return;
  const int lane = threadIdx.x & 63;
  const int l = lane >> 5;
  const int q = lane & 31;
  const char* zbase = (const char*)(zb + (size_t)l * GD);
  const uint qoff = (uint)q << 3;

  const int2* evr = ev + (size_t)g * CAP;
  int n = counts[g * CSTR];
  if (n > CAP) n = CAP;
  float4 acc = make_float4(0.f, 0.f, 0.f, 0.f);

  int i = 0;
  for (; i + 3 < n; i += 4) {
    int2 e0 = evr[i], e1 = evr[i + 1], e2 = evr[i + 2], e3 = evr[i + 3];
    ushort4 a0 = *reinterpret_cast<const ushort4*>(zbase + ((uint)e0.x + qoff));
    ushort4 a1 = *reinterpret_cast<const ushort4*>(zbase + ((uint)e1.x + qoff));
    ushort4 a2 = *reinterpret_cast<const ushort4*>(zbase + ((uint)e2.x + qoff));
    ushort4 a3 = *reinterpret_cast<const ushort4*>(zbase + ((uint)e3.x + qoff));
    float v0 = __int_as_float(e0.y), v1 = __int_as_float(e1.y);
    float v2 = __int_as_float(e2.y), v3 = __int_as_float(e3.y);
    acc.x += v0 * bf2f(a0.x) + v1 * bf2f(a1.x) + v2 * bf2f(a2.x) + v3 * bf2f(a3.x);
    acc.y += v0 * bf2f(a0.y) + v1 * bf2f(a1.y) + v2 * bf2f(a2.y) + v3 * bf2f(a3.y);
    acc.z += v0 * bf2f(a0.z) + v1 * bf2f(a1.z) + v2 * bf2f(a2.z) + v3 * bf2f(a3.z);
    acc.w += v0 * bf2f(a0.w) + v1 * bf2f(a1.w) + v2 * bf2f(a2.w) + v3 * bf2f(a3.w);
  }
  for (; i < n; ++i) {
    int2 e0 = evr[i];
    float v0 = __int_as_float(e0.y);
    ushort4 a0 = *reinterpret_cast<const ushort4*>(zbase + ((uint)e0.x + qoff));
    acc.x += v0 * bf2f(a0.x);
    acc.y += v0 * bf2f(a0.y);
    acc.z += v0 * bf2f(a0.z);
    acc.w += v0 * bf2f(a0.w);
  }

  // epilogue: bias + SiLU + LayerNorm (within the 32-lane half-wave)
  const int d0 = q * 4;
  const float4 bb = *reinterpret_cast<const float4*>(b + d0);
  float4 s;
  {
    float h0 = acc.x + bb.x, h1 = acc.y + bb.y;
    float h2 = acc.z + bb.z, h3 = acc.w + bb.w;
    s.x = h0 / (1.f + expf(-h0));
    s.y = h1 / (1.f + expf(-h1));
    s.z = h2 / (1.f + expf(-h2));
    s.w = h3 / (1.f + expf(-h3));
  }
  float sum = s.x + s.y + s.z + s.w;
  float sq = s.x * s.x + s.y * s.y + s.z * s.z + s.w * s.w;
#pragma unroll
  for (int m = 1; m <= 16; m <<= 1) {
    sum += __shfl_xor(sum, m);
    sq += __shfl_xor(sq, m);
  }
  const float mu = sum * (1.f / 128.f);
  const float var = sq * (1.f / 128.f) - mu * mu;
  const float inv = rsqrtf(var + 1e-5f);
  const float4 gm = *reinterpret_cast<const float4*>(gamma + d0);
  const float4 bt = *reinterpret_cast<const float4*>(beta + d0);
  float4 o;
  o.x = (s.x - mu) * inv * gm.x + bt.x;
  o.y = (s.y - mu) * inv * gm.y + bt.y;
  o.z = (s.z - mu) * inv * gm.z + bt.z;
  o.w = (s.w - mu) * inv * gm.w + bt.w;
  *reinterpret_cast<float4*>(out + (size_t)l * GD + (size_t)g * 128 + d0) = o;
}

// ---------------------------------------------------------------------------
extern "C" void kernel_launch(void* const* d_in, const int* in_sizes, int n_in,
                              void* d_out, int out_size, void* d_ws,
                              size_t ws_size, hipStream_t stream) {
  const float* x = (const float*)d_in[0];
  const int* rows = (const int*)d_in[1];
  const int* cols = (const int*)d_in[2];
  const float* vals = (const float*)d_in[3];
  const float* W = (const float*)d_in[4];
  const float* b = (const float*)d_in[5];
  const float* gamma = (const float*)d_in[6];
  const float* beta = (const float*)d_in[7];

  const int E = in_sizes[1];
  const int G = in_sizes[0] / 256;  // L=2, D=128
  const int GD = G * 128;

  // workspace layout:  zb (25.6 MB) | counts (3.2 MB padded) | Wb | ev (25.6 MB)
  char* ws = (char*)d_ws;
  ushort* zb = (ushort*)ws;                        // 2G*128 bf16
  int* counts = (int*)(zb + (size_t)2 * GD);       // G*CSTR ints
  ushort* Wb = (ushort*)(counts + (size_t)G * CSTR);  // 16384 bf16 (32 KB)
  int2* ev = (int2*)(Wb + 16384);                  // G*CAP int2

  prep_kernel<<<256, 256, 0, stream>>>(W, Wb, counts, G * CSTR);
  bucket_kernel<<<(E + 255) / 256, 256, 0, stream>>>(rows, cols, vals, counts,
                                                     ev, E);
  const int nstripes = (G * 2) / 16;
  zgemm_kernel<<<(nstripes + 4 * SPW - 1) / (4 * SPW), 256, 0, stream>>>(
      x, Wb, zb, nstripes);
  gather_fused_kernel<<<(G + 3) / 4, 256, 0, stream>>>(zb, counts, ev, b,
                                                       gamma, beta,
                                                       (float*)d_out, G, GD);
}